// Round 7
// baseline (297.672 us; speedup 1.0000x reference)
//
#include <hip/hip_runtime.h>
#include <math.h>

// ---------------------------------------------------------------------------
// 2-layer GCN. Two-key binning (dst-slice x src-region) + all-LDS aggregation.
//
// Evidence trail:
//  R2: global f32 atomicAdd = 32B HBM write each (~20G/s wall)  -> LDS agg.
//  R3: 4B scattered stores -> 32B sectors (5.7x write ampl)     -> LDS sort.
//  R4/R6: per-edge random gather (y[src]/zs[src]) saturates a ~82G line-req/s
//      wall (78.5us regardless of 16x more MLP). -> sort edges ALSO by src
//      region; stage the region's y/zs slice in LDS; per-edge ops all-LDS.
//
// Key layout: composite bucket c = (dst>>11)*R + (src>>13); R=13 regions,
// ND=49 dst-slices, NC=637. Packed record = (src<<11)|(dst&2047) (28 bits).
// Pipeline:
//   k_init   cursor[c] = c*CAP2
//   k_bin    per 8192-edge tile: composite hist -> scan -> reserve -> LDS
//            sort -> run-coalesced writeout
//   k_degB   per composite: LDS count[2048] -> u16 partial
//   k_node1  deg=sum_R(pdeg)+1; dinv=rsqrt; y=x*dinv
//   k_s1B    per composite: stage y-slice (32KB) -> LDS gather+atomic -> ps1
//   k_node2  s1=dinv*sum(ps1)+x/deg; 16x relu-FMA -> z; zs=z*dinv
//   k_s2B x2 per composite, half-region h: stage zs half-slice (32KB),
//            filter edges by half, LDS gather+atomic -> ps2 (h1 accumulates)
//   k_out    o=dinv*sum(ps2)+z/deg+b2; log_softmax
// Partials pdeg/ps1/ps2 time-share one region (sequential lifetimes).
// Valid for N <= 131072 (NC <= 768 with these bit splits).
// ---------------------------------------------------------------------------

#define DB      11          // dst-slice bits (2048 nodes)
#define DSLICE  2048
#define SB      13          // src-region bits (8192 nodes)
#define SREG    8192
#define CAP2    11264u      // per-composite capacity (mean ~10047 + >10 sigma)
#define TILE    8192
#define NCMAX   768

__global__ __launch_bounds__(256) void k_init(int NC, unsigned* __restrict__ cursor) {
    int c = blockIdx.x * 256 + threadIdx.x;
    if (c < NC) cursor[c] = (unsigned)c * CAP2;
}

__global__ __launch_bounds__(256) void k_bin(const int* __restrict__ src,
                                             const int* __restrict__ dst,
                                             int E, int R, int NC,
                                             unsigned* __restrict__ cursor,
                                             unsigned* __restrict__ binned) {
    __shared__ unsigned hist[NCMAX];
    __shared__ unsigned pfx[NCMAX];
    __shared__ unsigned lbase[NCMAX];
    __shared__ unsigned gbase[NCMAX];
    __shared__ unsigned svals[TILE];          // 32 KB
    __shared__ unsigned short sbkt[TILE];     // 16 KB

    const int lo = blockIdx.x * TILE;
    const int n  = min(E - lo, TILE);
    const int t  = threadIdx.x;
    const int n4 = n >> 2;

    for (int b = t; b < NCMAX; b += 256) hist[b] = 0;
    __syncthreads();

    const int4* d4 = (const int4*)(dst + lo);
    const int4* s4 = (const int4*)(src + lo);

    // Phase 1: composite-bucket histogram (int4 ILP)
    for (int j = t; j < n4; j += 256) {
        int4 d = d4[j]; int4 s = s4[j];
        atomicAdd(&hist[(((unsigned)d.x) >> DB) * R + (((unsigned)s.x) >> SB)], 1u);
        atomicAdd(&hist[(((unsigned)d.y) >> DB) * R + (((unsigned)s.y) >> SB)], 1u);
        atomicAdd(&hist[(((unsigned)d.z) >> DB) * R + (((unsigned)s.z) >> SB)], 1u);
        atomicAdd(&hist[(((unsigned)d.w) >> DB) * R + (((unsigned)s.w) >> SB)], 1u);
    }
    for (int j = (n4 << 2) + t; j < n; j += 256) {
        unsigned du = (unsigned)dst[lo + j], su = (unsigned)src[lo + j];
        atomicAdd(&hist[(du >> DB) * R + (su >> SB)], 1u);
    }
    __syncthreads();

    // Phase 2: inclusive scan over NCMAX=768 (3 slots/thread)
    for (int b = t; b < NCMAX; b += 256) pfx[b] = hist[b];
    __syncthreads();
    for (int off = 1; off < NCMAX; off <<= 1) {
        unsigned v0 = (t >= off) ? pfx[t - off] : 0u;
        unsigned v1 = (t + 256 >= off) ? pfx[t + 256 - off] : 0u;
        unsigned v2 = (t + 512 >= off) ? pfx[t + 512 - off] : 0u;
        __syncthreads();
        pfx[t]       += v0;
        pfx[t + 256] += v1;
        pfx[t + 512] += v2;
        __syncthreads();
    }
    for (int b = t; b < NC; b += 256) {
        unsigned c = hist[b];
        lbase[b] = pfx[b] - c;
        gbase[b] = c ? atomicAdd(&cursor[b], c) : 0u;
    }
    __syncthreads();
    for (int b = t; b < NCMAX; b += 256) hist[b] = 0;   // reuse as rank ctr
    __syncthreads();

    // Phase 3: rank + scatter into LDS, grouped by composite bucket
    for (int j = t; j < n4; j += 256) {
        int4 d = d4[j]; int4 s = s4[j];
        {
            unsigned du = (unsigned)d.x, su = (unsigned)s.x;
            unsigned cb = (du >> DB) * R + (su >> SB);
            unsigned pos = lbase[cb] + atomicAdd(&hist[cb], 1u);
            svals[pos] = (su << DB) | (du & (DSLICE - 1u));
            sbkt[pos]  = (unsigned short)cb;
        }
        {
            unsigned du = (unsigned)d.y, su = (unsigned)s.y;
            unsigned cb = (du >> DB) * R + (su >> SB);
            unsigned pos = lbase[cb] + atomicAdd(&hist[cb], 1u);
            svals[pos] = (su << DB) | (du & (DSLICE - 1u));
            sbkt[pos]  = (unsigned short)cb;
        }
        {
            unsigned du = (unsigned)d.z, su = (unsigned)s.z;
            unsigned cb = (du >> DB) * R + (su >> SB);
            unsigned pos = lbase[cb] + atomicAdd(&hist[cb], 1u);
            svals[pos] = (su << DB) | (du & (DSLICE - 1u));
            sbkt[pos]  = (unsigned short)cb;
        }
        {
            unsigned du = (unsigned)d.w, su = (unsigned)s.w;
            unsigned cb = (du >> DB) * R + (su >> SB);
            unsigned pos = lbase[cb] + atomicAdd(&hist[cb], 1u);
            svals[pos] = (su << DB) | (du & (DSLICE - 1u));
            sbkt[pos]  = (unsigned short)cb;
        }
    }
    for (int j = (n4 << 2) + t; j < n; j += 256) {
        unsigned du = (unsigned)dst[lo + j], su = (unsigned)src[lo + j];
        unsigned cb = (du >> DB) * R + (su >> SB);
        unsigned pos = lbase[cb] + atomicAdd(&hist[cb], 1u);
        svals[pos] = (su << DB) | (du & (DSLICE - 1u));
        sbkt[pos]  = (unsigned short)cb;
    }
    __syncthreads();

    // Phase 4: writeout — consecutive j share buckets => coalesced runs
    for (int j = t; j < n; j += 256) {
        unsigned cb = sbkt[j];
        binned[gbase[cb] + ((unsigned)j - lbase[cb])] = svals[j];
    }
}

__global__ __launch_bounds__(256) void k_degB(const unsigned* __restrict__ binned,
                                              const unsigned* __restrict__ cursor,
                                              unsigned short* __restrict__ pdeg) {
    __shared__ unsigned cnt[DSLICE];
    const int t = threadIdx.x;
    for (int k = t; k < DSLICE; k += 256) cnt[k] = 0;
    __syncthreads();
    const unsigned c = blockIdx.x;
    const unsigned lo = c * CAP2, hi = cursor[c];
    unsigned i = lo + t;
    for (; i + 768 < hi; i += 1024) {
        unsigned p0 = binned[i], p1 = binned[i + 256];
        unsigned p2 = binned[i + 512], p3 = binned[i + 768];
        atomicAdd(&cnt[p0 & (DSLICE - 1u)], 1u);
        atomicAdd(&cnt[p1 & (DSLICE - 1u)], 1u);
        atomicAdd(&cnt[p2 & (DSLICE - 1u)], 1u);
        atomicAdd(&cnt[p3 & (DSLICE - 1u)], 1u);
    }
    for (; i < hi; i += 256) atomicAdd(&cnt[binned[i] & (DSLICE - 1u)], 1u);
    __syncthreads();
    unsigned short* out = pdeg + (size_t)c * DSLICE;
    for (int k = t; k < DSLICE; k += 256) out[k] = (unsigned short)cnt[k];
}

__global__ __launch_bounds__(256) void k_node1(const unsigned short* __restrict__ pdeg,
                                               const float* __restrict__ x, int N, int R,
                                               float* __restrict__ deg,
                                               float* __restrict__ dinv,
                                               float* __restrict__ y) {
    const int g = blockIdx.x * 256 + threadIdx.x;
    if (g >= N) return;
    const int d = g >> DB, nlo = g & (DSLICE - 1);
    unsigned s = 0;
    for (int r = 0; r < R; ++r)
        s += pdeg[(size_t)(d * R + r) * DSLICE + nlo];
    float dg = (float)s + 1.0f;     // A + I
    float di = rsqrtf(dg);
    deg[g]  = dg;
    dinv[g] = di;
    y[g]    = x[g] * di;
}

__global__ __launch_bounds__(256) void k_s1B(const unsigned* __restrict__ binned,
                                             const unsigned* __restrict__ cursor,
                                             const float* __restrict__ y, int R, int N,
                                             float* __restrict__ ps1) {
    __shared__ float ysl[SREG];     // 32 KB
    __shared__ float acc[DSLICE];   // 8 KB
    const int t = threadIdx.x;
    const unsigned c = blockIdx.x;
    const int rg = (int)(c % (unsigned)R);
    const int base_src = rg << SB;
    const int nsrc = min(SREG, N - base_src);
    const int n4s = nsrc >> 2;
    const float4* y4 = (const float4*)(y + base_src);
    for (int k = t; k < n4s; k += 256) ((float4*)ysl)[k] = y4[k];
    for (int k = (n4s << 2) + t; k < nsrc; k += 256) ysl[k] = y[base_src + k];
    for (int k = t; k < DSLICE; k += 256) acc[k] = 0.0f;
    __syncthreads();
    const unsigned lo = c * CAP2, hi = cursor[c];
    unsigned i = lo + t;
    for (; i + 768 < hi; i += 1024) {
        unsigned p0 = binned[i], p1 = binned[i + 256];
        unsigned p2 = binned[i + 512], p3 = binned[i + 768];
        float v0 = ysl[(p0 >> DB) & (SREG - 1u)];
        float v1 = ysl[(p1 >> DB) & (SREG - 1u)];
        float v2 = ysl[(p2 >> DB) & (SREG - 1u)];
        float v3 = ysl[(p3 >> DB) & (SREG - 1u)];
        atomicAdd(&acc[p0 & (DSLICE - 1u)], v0);
        atomicAdd(&acc[p1 & (DSLICE - 1u)], v1);
        atomicAdd(&acc[p2 & (DSLICE - 1u)], v2);
        atomicAdd(&acc[p3 & (DSLICE - 1u)], v3);
    }
    for (; i < hi; i += 256) {
        unsigned p = binned[i];
        atomicAdd(&acc[p & (DSLICE - 1u)], ysl[(p >> DB) & (SREG - 1u)]);
    }
    __syncthreads();
    float* out = ps1 + (size_t)c * DSLICE;
    for (int k = t; k < DSLICE; k += 256) out[k] = acc[k];
}

__global__ __launch_bounds__(256) void k_node2(const float* __restrict__ ps1,
                                               const float* __restrict__ x,
                                               const float* __restrict__ deg,
                                               const float* __restrict__ dinv,
                                               const float* __restrict__ W1,
                                               const float* __restrict__ b1,
                                               const float* __restrict__ W2,
                                               int N, int R,
                                               float* __restrict__ z,
                                               float* __restrict__ zs) {
    const int g = blockIdx.x * 256 + threadIdx.x;
    if (g >= N) return;
    const int d = g >> DB, nlo = g & (DSLICE - 1);
    float sa = 0.0f;
    for (int r = 0; r < R; ++r)
        sa += ps1[(size_t)(d * R + r) * DSLICE + nlo];
    float di = dinv[g];
    float s1 = fmaf(di, sa, x[g] / deg[g]);
    float z0 = 0.0f, z1 = 0.0f;
#pragma unroll
    for (int f = 0; f < 16; ++f) {
        float h = fmaxf(fmaf(s1, W1[f], b1[f]), 0.0f);
        z0 = fmaf(h, W2[2 * f + 0], z0);
        z1 = fmaf(h, W2[2 * f + 1], z1);
    }
    ((float2*)z)[g]  = make_float2(z0, z1);
    ((float2*)zs)[g] = make_float2(z0 * di, z1 * di);
}

// Half-region pass: h selects src sub-slice of 4096; h=1 accumulates into ps2.
__global__ __launch_bounds__(256) void k_s2B(const unsigned* __restrict__ binned,
                                             const unsigned* __restrict__ cursor,
                                             const float* __restrict__ zs,
                                             int R, int N, int h,
                                             float2* __restrict__ ps2) {
    __shared__ float2 zsl[SREG / 2];          // 32 KB
    __shared__ float a0[DSLICE], a1[DSLICE];  // 16 KB
    const int t = threadIdx.x;
    const unsigned c = blockIdx.x;
    const int rg = (int)(c % (unsigned)R);
    const int base_src = (rg << SB) + h * (SREG / 2);
    const int nsrc = max(0, min(SREG / 2, N - base_src));
    const float2* zsg = ((const float2*)zs) + base_src;
    const int n4s = nsrc >> 1;                // float4 count
    for (int k = t; k < n4s; k += 256) ((float4*)zsl)[k] = ((const float4*)zsg)[k];
    if ((nsrc & 1) && t == 0) zsl[nsrc - 1] = zsg[nsrc - 1];
    for (int k = t; k < DSLICE; k += 256) { a0[k] = 0.0f; a1[k] = 0.0f; }
    __syncthreads();
    const unsigned lo = c * CAP2, hi = cursor[c];
    const unsigned hu = (unsigned)h;
    unsigned i = lo + t;
    for (; i + 768 < hi; i += 1024) {
        unsigned p0 = binned[i], p1 = binned[i + 256];
        unsigned p2 = binned[i + 512], p3 = binned[i + 768];
        unsigned s0 = (p0 >> DB) & (SREG - 1u);
        unsigned s1x = (p1 >> DB) & (SREG - 1u);
        unsigned s2x = (p2 >> DB) & (SREG - 1u);
        unsigned s3x = (p3 >> DB) & (SREG - 1u);
        if ((s0 >> 12) == hu) {
            float2 v = zsl[s0 & 4095u];
            atomicAdd(&a0[p0 & (DSLICE - 1u)], v.x);
            atomicAdd(&a1[p0 & (DSLICE - 1u)], v.y);
        }
        if ((s1x >> 12) == hu) {
            float2 v = zsl[s1x & 4095u];
            atomicAdd(&a0[p1 & (DSLICE - 1u)], v.x);
            atomicAdd(&a1[p1 & (DSLICE - 1u)], v.y);
        }
        if ((s2x >> 12) == hu) {
            float2 v = zsl[s2x & 4095u];
            atomicAdd(&a0[p2 & (DSLICE - 1u)], v.x);
            atomicAdd(&a1[p2 & (DSLICE - 1u)], v.y);
        }
        if ((s3x >> 12) == hu) {
            float2 v = zsl[s3x & 4095u];
            atomicAdd(&a0[p3 & (DSLICE - 1u)], v.x);
            atomicAdd(&a1[p3 & (DSLICE - 1u)], v.y);
        }
    }
    for (; i < hi; i += 256) {
        unsigned p = binned[i];
        unsigned sx = (p >> DB) & (SREG - 1u);
        if ((sx >> 12) == hu) {
            float2 v = zsl[sx & 4095u];
            atomicAdd(&a0[p & (DSLICE - 1u)], v.x);
            atomicAdd(&a1[p & (DSLICE - 1u)], v.y);
        }
    }
    __syncthreads();
    float2* out = ps2 + (size_t)c * DSLICE;
    if (h == 0) {
        for (int k = t; k < DSLICE; k += 256) out[k] = make_float2(a0[k], a1[k]);
    } else {
        for (int k = t; k < DSLICE; k += 256) {
            float2 prev = out[k];
            out[k] = make_float2(prev.x + a0[k], prev.y + a1[k]);
        }
    }
}

__global__ __launch_bounds__(256) void k_out(const float2* __restrict__ ps2,
                                             const float* __restrict__ deg,
                                             const float* __restrict__ dinv,
                                             const float* __restrict__ z,
                                             const float* __restrict__ b2,
                                             int N, int R,
                                             float* __restrict__ out) {
    const int g = blockIdx.x * 256 + threadIdx.x;
    if (g >= N) return;
    const int d = g >> DB, nlo = g & (DSLICE - 1);
    float a0 = 0.0f, a1 = 0.0f;
    for (int r = 0; r < R; ++r) {
        float2 p = ps2[(size_t)(d * R + r) * DSLICE + nlo];
        a0 += p.x;
        a1 += p.y;
    }
    float di   = dinv[g];
    float invd = 1.0f / deg[g];
    float2 zz  = ((const float2*)z)[g];
    float o0 = fmaf(di, a0, zz.x * invd) + b2[0];
    float o1 = fmaf(di, a1, zz.y * invd) + b2[1];
    float m   = fmaxf(o0, o1);
    float lse = m + __logf(__expf(o0 - m) + __expf(o1 - m));
    ((float2*)out)[g] = make_float2(o0 - lse, o1 - lse);
}

extern "C" void kernel_launch(void* const* d_in, const int* in_sizes, int n_in,
                              void* d_out, int out_size, void* d_ws, size_t ws_size,
                              hipStream_t stream) {
    const float* x  = (const float*)d_in[0];
    const int*   ei = (const int*)d_in[1];
    const float* W1 = (const float*)d_in[2];
    const float* b1 = (const float*)d_in[3];
    const float* W2 = (const float*)d_in[4];
    const float* b2 = (const float*)d_in[5];

    const int N = in_sizes[0];      // x is [N, 1]
    const int E = in_sizes[1] / 2;  // edge_index is [2, E]
    const int* src = ei;
    const int* dst = ei + E;

    const int ND = (N + DSLICE - 1) >> DB;  // 49 dst-slices
    const int R  = (N + SREG - 1) >> SB;    // 13 src-regions
    const int NC = ND * R;                  // 637 composite buckets (<= NCMAX)

    // Workspace (~41.9 MB). pdeg/ps1/ps2 time-share region X (sequential lifetimes).
    char* p = (char*)d_ws;
    unsigned* binned2 = (unsigned*)p;  p += (size_t)NC * CAP2 * 4;     // 28.7 MB
    char* X = p;                       p += (size_t)NC * DSLICE * 8;   // 10.4 MB
    float* deg  = (float*)p;           p += (size_t)N * 4;
    float* dinv = (float*)p;           p += (size_t)N * 4;
    float* y    = (float*)p;           p += (size_t)N * 4;
    float* z    = (float*)p;           p += (size_t)2 * N * 4;
    float* zs   = (float*)p;           p += (size_t)2 * N * 4;
    unsigned* cursor = (unsigned*)p;   p += (size_t)NC * 4;

    unsigned short* pdeg = (unsigned short*)X;  // k_degB .. k_node1
    float*          ps1  = (float*)X;           // k_s1B  .. k_node2
    float2*         ps2  = (float2*)X;          // k_s2B  .. k_out

    const int nb_bin  = (E + TILE - 1) / TILE;
    const int nb_node = (N + 255) / 256;

    k_init  <<<(NC + 255) / 256, 256, 0, stream>>>(NC, cursor);
    k_bin   <<<nb_bin, 256, 0, stream>>>(src, dst, E, R, NC, cursor, binned2);
    k_degB  <<<NC, 256, 0, stream>>>(binned2, cursor, pdeg);
    k_node1 <<<nb_node, 256, 0, stream>>>(pdeg, x, N, R, deg, dinv, y);
    k_s1B   <<<NC, 256, 0, stream>>>(binned2, cursor, y, R, N, ps1);
    k_node2 <<<nb_node, 256, 0, stream>>>(ps1, x, deg, dinv, W1, b1, W2, N, R, z, zs);
    k_s2B   <<<NC, 256, 0, stream>>>(binned2, cursor, zs, R, N, 0, ps2);
    k_s2B   <<<NC, 256, 0, stream>>>(binned2, cursor, zs, R, N, 1, ps2);
    k_out   <<<nb_node, 256, 0, stream>>>(ps2, deg, dinv, z, b2, N, R, (float*)d_out);
}

// Round 8
// 241.211 us; speedup vs baseline: 1.2341x; 1.2341x over previous
//
#include <hip/hip_runtime.h>
#include <math.h>

// ---------------------------------------------------------------------------
// 2-layer GCN: counting-sort edges by dst, then ATOMIC-FREE segmented sums.
//
// Evidence trail:
//  R2: global f32 atomicAdd = 32B HBM write each (~20G/s wall)  -> LDS agg.
//  R3: 4B scattered stores -> 32B sectors (5.7x write ampl)     -> LDS sort.
//  R7: LDS f32 atomic RMW throughput (~4.3us per M ops chip-wide) is THE
//      wall (k_s2B = 51us with all gathers in LDS; R6->R7 delta tracks
//      atomic count exactly). -> full counting sort (int atomics confined
//      to bin+sort), then all aggregations are atomic-free segmented sums.
//
// Pipeline:
//   k_init  cursor[b] = b*CAP
//   k_bin   8192-edge tiles: LDS multisplit by dst>>8 -> binned[] (R4-proven)
//   k_sort  per bucket: stage in LDS, 256-hist, scan -> sorted[] grouped by
//           node; fuses deg/dinv/y (hist IS deg) and writes off[]
//   k_agg1  4 thr/node: sum y[sorted[run]] -> s1 -> 16x relu-FMA -> z, zs
//   k_agg2  4 thr/node: sum zs[sorted[run]] (float2) -> o -> log_softmax
// Valid for N <= 131072 (NB <= 512), uniform-ish dst (CAP = mean+8sigma).
// ---------------------------------------------------------------------------

#define NB_MAX 512
#define CAP    17408u   // per-bucket capacity: E/NB=16368 avg, +8 sigma
#define TILE   8192

__global__ __launch_bounds__(512) void k_init(int NB, unsigned* __restrict__ cursor) {
    int b = threadIdx.x;
    if (b < NB) cursor[b] = (unsigned)b * CAP;
}

__global__ __launch_bounds__(256) void k_bin(const int* __restrict__ src,
                                             const int* __restrict__ dst, int E, int NB,
                                             unsigned* __restrict__ cursor,
                                             unsigned* __restrict__ binned) {
    __shared__ unsigned hist[NB_MAX];
    __shared__ unsigned scan[NB_MAX];
    __shared__ unsigned lbase[NB_MAX];
    __shared__ unsigned gbase[NB_MAX];
    __shared__ unsigned svals[TILE];          // 32 KB
    __shared__ unsigned short sbkt[TILE];     // 16 KB

    const int lo = blockIdx.x * TILE;
    const int n  = min(E - lo, TILE);
    const int t  = threadIdx.x;
    const int n4 = n >> 2;

    for (int b = t; b < NB_MAX; b += 256) hist[b] = 0;
    __syncthreads();

    const int4* d4 = (const int4*)(dst + lo);
    const int4* s4 = (const int4*)(src + lo);

    // Phase 1: per-tile bucket histogram (int4 ILP)
    for (int j = t; j < n4; j += 256) {
        int4 d = d4[j];
        atomicAdd(&hist[((unsigned)d.x) >> 8], 1u);
        atomicAdd(&hist[((unsigned)d.y) >> 8], 1u);
        atomicAdd(&hist[((unsigned)d.z) >> 8], 1u);
        atomicAdd(&hist[((unsigned)d.w) >> 8], 1u);
    }
    for (int j = (n4 << 2) + t; j < n; j += 256)
        atomicAdd(&hist[((unsigned)dst[lo + j]) >> 8], 1u);
    __syncthreads();

    // Phase 2: inclusive Hillis-Steele scan over NB_MAX (2 slots/thread)
    for (int b = t; b < NB_MAX; b += 256) scan[b] = hist[b];
    __syncthreads();
    for (int off = 1; off < NB_MAX; off <<= 1) {
        int i0 = t, i1 = t + 256;
        unsigned v0 = (i0 >= off) ? scan[i0 - off] : 0u;
        unsigned v1 = (i1 >= off) ? scan[i1 - off] : 0u;
        __syncthreads();
        if (i0 >= off) scan[i0] += v0;
        if (i1 >= off) scan[i1] += v1;
        __syncthreads();
    }
    for (int b = t; b < NB; b += 256) {
        unsigned c = hist[b];
        lbase[b] = scan[b] - c;
        gbase[b] = c ? atomicAdd(&cursor[b], c) : 0u;
    }
    __syncthreads();
    for (int b = t; b < NB_MAX; b += 256) hist[b] = 0;   // reuse as rank ctr
    __syncthreads();

    // Phase 3: rank + scatter into LDS, grouped by bucket (int4 ILP)
    for (int j = t; j < n4; j += 256) {
        int4 d = d4[j];
        int4 s = s4[j];
        {
            unsigned du = (unsigned)d.x;
            unsigned b = du >> 8;
            unsigned pos = lbase[b] + atomicAdd(&hist[b], 1u);
            svals[pos] = (((unsigned)s.x) << 8) | (du & 255u);
            sbkt[pos]  = (unsigned short)b;
        }
        {
            unsigned du = (unsigned)d.y;
            unsigned b = du >> 8;
            unsigned pos = lbase[b] + atomicAdd(&hist[b], 1u);
            svals[pos] = (((unsigned)s.y) << 8) | (du & 255u);
            sbkt[pos]  = (unsigned short)b;
        }
        {
            unsigned du = (unsigned)d.z;
            unsigned b = du >> 8;
            unsigned pos = lbase[b] + atomicAdd(&hist[b], 1u);
            svals[pos] = (((unsigned)s.z) << 8) | (du & 255u);
            sbkt[pos]  = (unsigned short)b;
        }
        {
            unsigned du = (unsigned)d.w;
            unsigned b = du >> 8;
            unsigned pos = lbase[b] + atomicAdd(&hist[b], 1u);
            svals[pos] = (((unsigned)s.w) << 8) | (du & 255u);
            sbkt[pos]  = (unsigned short)b;
        }
    }
    for (int j = (n4 << 2) + t; j < n; j += 256) {
        unsigned du = (unsigned)dst[lo + j];
        unsigned b = du >> 8;
        unsigned pos = lbase[b] + atomicAdd(&hist[b], 1u);
        svals[pos] = (((unsigned)src[lo + j]) << 8) | (du & 255u);
        sbkt[pos]  = (unsigned short)b;
    }
    __syncthreads();

    // Phase 4: writeout — consecutive j share buckets => coalesced runs
    for (int j = t; j < n; j += 256) {
        unsigned b = sbkt[j];
        binned[gbase[b] + ((unsigned)j - lbase[b])] = svals[j];
    }
}

// Per bucket: full sort by node + fused deg/dinv/y/off (old node pass 1).
__global__ __launch_bounds__(256) void k_sort(const unsigned* __restrict__ binned,
                                              const unsigned* __restrict__ cursor,
                                              const float* __restrict__ x, int N,
                                              unsigned* __restrict__ sorted,
                                              unsigned* __restrict__ off,
                                              float* __restrict__ deg,
                                              float* __restrict__ dinv,
                                              float* __restrict__ y) {
    __shared__ unsigned stage[CAP];   // 69632 B
    __shared__ unsigned hist[256];
    __shared__ unsigned incl[256];
    __shared__ unsigned exS[256];
    __shared__ unsigned rk[256];
    const int t = threadIdx.x;
    const unsigned b   = blockIdx.x;
    const unsigned lo  = b * CAP;
    const unsigned cnt = cursor[b] - lo;
    hist[t] = 0;
    rk[t]   = 0;
    __syncthreads();

    // Load bucket into LDS + per-node histogram (4-way ILP)
    {
        unsigned i = t;
        for (; i + 768 < cnt; i += 1024) {
            unsigned p0 = binned[lo + i];
            unsigned p1 = binned[lo + i + 256];
            unsigned p2 = binned[lo + i + 512];
            unsigned p3 = binned[lo + i + 768];
            stage[i]       = p0;
            stage[i + 256] = p1;
            stage[i + 512] = p2;
            stage[i + 768] = p3;
            atomicAdd(&hist[p0 & 255u], 1u);
            atomicAdd(&hist[p1 & 255u], 1u);
            atomicAdd(&hist[p2 & 255u], 1u);
            atomicAdd(&hist[p3 & 255u], 1u);
        }
        for (; i < cnt; i += 256) {
            unsigned p = binned[lo + i];
            stage[i] = p;
            atomicAdd(&hist[p & 255u], 1u);
        }
    }
    __syncthreads();

    // Inclusive scan over 256 node counts
    incl[t] = hist[t];
    __syncthreads();
    for (int o = 1; o < 256; o <<= 1) {
        unsigned v = (t >= o) ? incl[t - o] : 0u;
        __syncthreads();
        incl[t] += v;
        __syncthreads();
    }
    exS[t] = incl[t] - hist[t];

    // Fused node pass: deg = hist+1 (A+I), dinv, y, run offset
    const int g = (int)(b << 8) + t;
    if (g < N) {
        float d  = (float)hist[t] + 1.0f;
        float di = rsqrtf(d);
        deg[g]  = d;
        dinv[g] = di;
        y[g]    = x[g] * di;
        off[g]  = lo + exS[t];
    }
    __syncthreads();

    // Rank-scatter to final per-node-sorted positions (payload = src index)
    {
        unsigned i = t;
        for (; i + 768 < cnt; i += 1024) {
            unsigned p0 = stage[i];
            unsigned p1 = stage[i + 256];
            unsigned p2 = stage[i + 512];
            unsigned p3 = stage[i + 768];
            unsigned l0 = p0 & 255u, l1 = p1 & 255u;
            unsigned l2 = p2 & 255u, l3 = p3 & 255u;
            sorted[lo + exS[l0] + atomicAdd(&rk[l0], 1u)] = p0 >> 8;
            sorted[lo + exS[l1] + atomicAdd(&rk[l1], 1u)] = p1 >> 8;
            sorted[lo + exS[l2] + atomicAdd(&rk[l2], 1u)] = p2 >> 8;
            sorted[lo + exS[l3] + atomicAdd(&rk[l3], 1u)] = p3 >> 8;
        }
        for (; i < cnt; i += 256) {
            unsigned p = stage[i];
            unsigned l = p & 255u;
            sorted[lo + exS[l] + atomicAdd(&rk[l], 1u)] = p >> 8;
        }
    }
}

// 4 threads/node: atomic-free segmented sum of y[src]; fused layer-2 MLP.
__global__ __launch_bounds__(256) void k_agg1(const unsigned* __restrict__ sorted,
                                              const unsigned* __restrict__ off,
                                              const float* __restrict__ deg,
                                              const float* __restrict__ dinv,
                                              const float* __restrict__ x,
                                              const float* __restrict__ y,
                                              const float* __restrict__ W1,
                                              const float* __restrict__ b1,
                                              const float* __restrict__ W2, int N,
                                              float* __restrict__ z,
                                              float* __restrict__ zs) {
    const int tid = blockIdx.x * 256 + threadIdx.x;
    const int g   = tid >> 2;
    const int h   = tid & 3;
    if (g >= N) return;
    const float d   = deg[g];
    const int   n   = (int)d - 1;          // edge count of this node
    const unsigned lo = off[g];
    float acc = 0.0f;
    int i = h;
    for (; i + 4 < n; i += 8) {            // 2 independent gather chains
        unsigned s0 = sorted[lo + i];
        unsigned s1 = sorted[lo + i + 4];
        acc += y[s0];
        acc += y[s1];
    }
    for (; i < n; i += 4) acc += y[sorted[lo + i]];
    acc += __shfl_xor(acc, 1);
    acc += __shfl_xor(acc, 2);
    // all 4 lanes now hold the full sum; redundant compute, lane 0 stores
    float di = dinv[g];
    float s1v = fmaf(di, acc, x[g] / d);
    float z0 = 0.0f, z1 = 0.0f;
#pragma unroll
    for (int f = 0; f < 16; ++f) {
        float hh = fmaxf(fmaf(s1v, W1[f], b1[f]), 0.0f);
        z0 = fmaf(hh, W2[2 * f + 0], z0);
        z1 = fmaf(hh, W2[2 * f + 1], z1);
    }
    if (h == 0) {
        ((float2*)z)[g]  = make_float2(z0, z1);
        ((float2*)zs)[g] = make_float2(z0 * di, z1 * di);
    }
}

// 4 threads/node: atomic-free segmented sum of zs[src]; fused log_softmax.
__global__ __launch_bounds__(256) void k_agg2(const unsigned* __restrict__ sorted,
                                              const unsigned* __restrict__ off,
                                              const float* __restrict__ deg,
                                              const float* __restrict__ dinv,
                                              const float* __restrict__ z,
                                              const float* __restrict__ zs,
                                              const float* __restrict__ b2, int N,
                                              float* __restrict__ out) {
    const int tid = blockIdx.x * 256 + threadIdx.x;
    const int g   = tid >> 2;
    const int h   = tid & 3;
    if (g >= N) return;
    const float d   = deg[g];
    const int   n   = (int)d - 1;
    const unsigned lo = off[g];
    const float2* zs2 = (const float2*)zs;
    float a0 = 0.0f, a1 = 0.0f;
    int i = h;
    for (; i + 4 < n; i += 8) {
        unsigned s0 = sorted[lo + i];
        unsigned s1 = sorted[lo + i + 4];
        float2 v0 = zs2[s0];
        float2 v1 = zs2[s1];
        a0 += v0.x + v1.x;
        a1 += v0.y + v1.y;
    }
    for (; i < n; i += 4) {
        float2 v = zs2[sorted[lo + i]];
        a0 += v.x;
        a1 += v.y;
    }
    a0 += __shfl_xor(a0, 1);
    a0 += __shfl_xor(a0, 2);
    a1 += __shfl_xor(a1, 1);
    a1 += __shfl_xor(a1, 2);
    if (h == 0) {
        float di   = dinv[g];
        float invd = 1.0f / d;
        float2 zz  = ((const float2*)z)[g];
        float o0 = fmaf(di, a0, zz.x * invd) + b2[0];
        float o1 = fmaf(di, a1, zz.y * invd) + b2[1];
        float m   = fmaxf(o0, o1);
        float lse = m + __logf(__expf(o0 - m) + __expf(o1 - m));
        ((float2*)out)[g] = make_float2(o0 - lse, o1 - lse);
    }
}

extern "C" void kernel_launch(void* const* d_in, const int* in_sizes, int n_in,
                              void* d_out, int out_size, void* d_ws, size_t ws_size,
                              hipStream_t stream) {
    const float* x  = (const float*)d_in[0];
    const int*   ei = (const int*)d_in[1];
    const float* W1 = (const float*)d_in[2];
    const float* b1 = (const float*)d_in[3];
    const float* W2 = (const float*)d_in[4];
    const float* b2 = (const float*)d_in[5];

    const int N = in_sizes[0];      // x is [N, 1]
    const int E = in_sizes[1] / 2;  // edge_index is [2, E]
    const int* src = ei;
    const int* dst = ei + E;

    const int NB = (N + 255) >> 8;  // 256-node buckets, NB <= 512

    // Workspace. z/zs alias the binned region (binned dead after k_sort).
    char* p = (char*)d_ws;
    unsigned* binned = (unsigned*)p;  p += ((size_t)NB * CAP + TILE) * 4;  // ~27.3 MB
    unsigned* sorted = (unsigned*)p;  p += (size_t)NB * CAP * 4;           // ~27.2 MB
    unsigned* off    = (unsigned*)p;  p += (size_t)N * 4;
    float* deg  = (float*)p;          p += (size_t)N * 4;
    float* dinv = (float*)p;          p += (size_t)N * 4;
    float* y    = (float*)p;          p += (size_t)N * 4;
    unsigned* cursor = (unsigned*)p;  p += (size_t)NB_MAX * 4;
    float* z  = (float*)binned;              // [2N] written in k_agg1
    float* zs = ((float*)binned) + 2 * (size_t)N;  // [2N]

    const int nb_bin = (E + TILE - 1) / TILE;
    const int nb_agg = (4 * N + 255) / 256;

    k_init <<<1, 512, 0, stream>>>(NB, cursor);
    k_bin  <<<nb_bin, 256, 0, stream>>>(src, dst, E, NB, cursor, binned);
    k_sort <<<NB, 256, 0, stream>>>(binned, cursor, x, N, sorted, off, deg, dinv, y);
    k_agg1 <<<nb_agg, 256, 0, stream>>>(sorted, off, deg, dinv, x, y, W1, b1, W2, N, z, zs);
    k_agg2 <<<nb_agg, 256, 0, stream>>>(sorted, off, deg, dinv, z, zs, b2, N, (float*)d_out);
}

// Round 9
// 239.022 us; speedup vs baseline: 1.2454x; 1.0092x over previous
//
#include <hip/hip_runtime.h>
#include <math.h>

// ---------------------------------------------------------------------------
// 2-layer GCN: counting-sort edges by dst, then ATOMIC-FREE segmented sums.
//
// Evidence trail:
//  R2: global f32 atomicAdd = 32B HBM write each (~20G/s wall)  -> LDS agg.
//  R3: 4B scattered stores -> 32B sectors (5.7x write ampl)     -> LDS sort.
//  R7: LDS f32 atomic RMW throughput is THE wall (~4.3us/M chip-wide at low
//      occupancy); aggregation must be atomic-free.
//  R8: bin+sort now dominate; both spend 2 LDS atomics/edge at <=2 blocks/CU.
//      -> 1 atomic/edge (rank-at-load, permute via plain LDS writes),
//         32KB LDS k_bin (5 blocks/CU), stage-free 1024-thread k_sort,
//         8 threads/node aggs.
//
// Pipeline:
//   k_init  cursor[b] = b*CAP
//   k_bin   4096-edge tiles: reg-held rank multisplit by dst>>8 -> binned[]
//   k_sort  per bucket (1024 thr): global 2-pass hist+rank -> sorted[] by
//           node; fuses deg/dinv/y (hist IS deg) and writes off[]
//   k_agg1  8 thr/node: sum y[sorted[run]] -> s1 -> 16x relu-FMA -> z, zs
//   k_agg2  8 thr/node: sum zs[sorted[run]] (float2) -> o -> log_softmax
// Valid for N <= 131072 (NB <= 512), uniform-ish dst (CAP = mean+8sigma).
// ---------------------------------------------------------------------------

#define NB_MAX 512
#define CAP    17408u   // per-bucket capacity: E/NB=16368 avg, +8 sigma
#define TILE   4096
#define EPT    16       // edges per thread in k_bin (TILE/256)

__global__ __launch_bounds__(512) void k_init(int NB, unsigned* __restrict__ cursor) {
    int b = threadIdx.x;
    if (b < NB) cursor[b] = (unsigned)b * CAP;
}

// Multisplit by dst>>8. ONE LDS atomic per edge (rank at load, held in regs),
// then scan -> LDS permute (plain writes) -> coalesced writeout.
__global__ __launch_bounds__(256) void k_bin(const int* __restrict__ src,
                                             const int* __restrict__ dst, int E, int NB,
                                             unsigned* __restrict__ cursor,
                                             unsigned* __restrict__ binned) {
    __shared__ unsigned cnt[NB_MAX];      // 2 KB
    __shared__ unsigned pfx[NB_MAX];      // 2 KB
    __shared__ unsigned lbase[NB_MAX];    // 2 KB
    __shared__ unsigned gbase[NB_MAX];    // 2 KB
    __shared__ unsigned svals[TILE];      // 16 KB
    __shared__ unsigned short sbkt[TILE]; // 8 KB   => ~32 KB total

    const int lo = blockIdx.x * TILE;
    const int n  = min(E - lo, TILE);
    const int t  = threadIdx.x;
    const int nq    = n >> 2;             // int4 count
    const int ntail = n - (nq << 2);      // 0..3 leftover edges

    for (int b = t; b < NB_MAX; b += 256) cnt[b] = 0;
    __syncthreads();

    const int4* d4 = (const int4*)(dst + lo);
    const int4* s4 = (const int4*)(src + lo);

    unsigned val[EPT];
    unsigned brk[EPT];                    // (bucket<<13) | rank ; 0xFFFFFFFF = invalid

#pragma unroll
    for (int k = 0; k < 4; ++k) {
        const int j = t + (k << 8);
        if (j < nq) {
            int4 d = d4[j];
            int4 s = s4[j];
            {
                unsigned du = (unsigned)d.x, su = (unsigned)s.x;
                unsigned b = du >> 8;
                unsigned r = atomicAdd(&cnt[b], 1u);
                val[k * 4 + 0] = (su << 8) | (du & 255u);
                brk[k * 4 + 0] = (b << 13) | r;
            }
            {
                unsigned du = (unsigned)d.y, su = (unsigned)s.y;
                unsigned b = du >> 8;
                unsigned r = atomicAdd(&cnt[b], 1u);
                val[k * 4 + 1] = (su << 8) | (du & 255u);
                brk[k * 4 + 1] = (b << 13) | r;
            }
            {
                unsigned du = (unsigned)d.z, su = (unsigned)s.z;
                unsigned b = du >> 8;
                unsigned r = atomicAdd(&cnt[b], 1u);
                val[k * 4 + 2] = (su << 8) | (du & 255u);
                brk[k * 4 + 2] = (b << 13) | r;
            }
            {
                unsigned du = (unsigned)d.w, su = (unsigned)s.w;
                unsigned b = du >> 8;
                unsigned r = atomicAdd(&cnt[b], 1u);
                val[k * 4 + 3] = (su << 8) | (du & 255u);
                brk[k * 4 + 3] = (b << 13) | r;
            }
        } else {
            brk[k * 4 + 0] = 0xFFFFFFFFu;
            brk[k * 4 + 1] = 0xFFFFFFFFu;
            brk[k * 4 + 2] = 0xFFFFFFFFu;
            brk[k * 4 + 3] = 0xFFFFFFFFu;
            val[k * 4 + 0] = 0; val[k * 4 + 1] = 0;
            val[k * 4 + 2] = 0; val[k * 4 + 3] = 0;
        }
    }
    // tail edges (n % 4), one per thread t < ntail
    unsigned tval = 0, tbrk = 0xFFFFFFFFu;
    if (t < ntail) {
        unsigned du = (unsigned)dst[lo + (nq << 2) + t];
        unsigned su = (unsigned)src[lo + (nq << 2) + t];
        unsigned b = du >> 8;
        unsigned r = atomicAdd(&cnt[b], 1u);
        tval = (su << 8) | (du & 255u);
        tbrk = (b << 13) | r;
    }
    __syncthreads();

    // Inclusive scan over 512 bucket counts (2 slots/thread)
    pfx[t]       = cnt[t];
    pfx[t + 256] = cnt[t + 256];
    __syncthreads();
    for (int o = 1; o < NB_MAX; o <<= 1) {
        unsigned v0 = (t >= o) ? pfx[t - o] : 0u;
        unsigned v1 = (t + 256 >= o) ? pfx[t + 256 - o] : 0u;
        __syncthreads();
        if (t >= o) pfx[t] += v0;
        pfx[t + 256] += v1;   // t+256 >= 256 >= o always true for o<=256... guard:
        __syncthreads();
    }
    for (int b = t; b < NB_MAX; b += 256) {
        unsigned c = cnt[b];
        lbase[b] = pfx[b] - c;
        gbase[b] = (b < NB && c) ? atomicAdd(&cursor[b], c) : 0u;
    }
    __syncthreads();

    // LDS permute: place each held edge at its in-tile sorted position
#pragma unroll
    for (int k = 0; k < EPT; ++k) {
        if (brk[k] != 0xFFFFFFFFu) {
            unsigned b = brk[k] >> 13, r = brk[k] & 8191u;
            unsigned pos = lbase[b] + r;
            svals[pos] = val[k];
            sbkt[pos]  = (unsigned short)b;
        }
    }
    if (tbrk != 0xFFFFFFFFu) {
        unsigned b = tbrk >> 13, r = tbrk & 8191u;
        unsigned pos = lbase[b] + r;
        svals[pos] = tval;
        sbkt[pos]  = (unsigned short)b;
    }
    __syncthreads();

    // Coalesced writeout: consecutive j share buckets => contiguous runs
    for (int j = t; j < n; j += 256) {
        unsigned b = sbkt[j];
        binned[gbase[b] + ((unsigned)j - lbase[b])] = svals[j];
    }
}

// Per bucket, 1024 threads, ~4KB LDS: two global passes over binned
// (L3-resident). Fuses deg/dinv/y/off node pass.
__global__ __launch_bounds__(1024) void k_sort(const unsigned* __restrict__ binned,
                                               const unsigned* __restrict__ cursor,
                                               const float* __restrict__ x, int N,
                                               unsigned* __restrict__ sorted,
                                               unsigned* __restrict__ off,
                                               float* __restrict__ deg,
                                               float* __restrict__ dinv,
                                               float* __restrict__ y) {
    __shared__ unsigned hist[256];
    __shared__ unsigned incl[256];
    __shared__ unsigned exS[256];
    __shared__ unsigned rk[256];
    const int t = threadIdx.x;
    const unsigned b   = blockIdx.x;
    const unsigned lo  = b * CAP;
    const unsigned cnt = cursor[b] - lo;
    if (t < 256) { hist[t] = 0; rk[t] = 0; }
    __syncthreads();

    // Phase A: per-node histogram (4-way ILP, stride 1024)
    {
        unsigned i = t;
        for (; i + 3072 < cnt; i += 4096) {
            unsigned p0 = binned[lo + i];
            unsigned p1 = binned[lo + i + 1024];
            unsigned p2 = binned[lo + i + 2048];
            unsigned p3 = binned[lo + i + 3072];
            atomicAdd(&hist[p0 & 255u], 1u);
            atomicAdd(&hist[p1 & 255u], 1u);
            atomicAdd(&hist[p2 & 255u], 1u);
            atomicAdd(&hist[p3 & 255u], 1u);
        }
        for (; i < cnt; i += 1024) atomicAdd(&hist[binned[lo + i] & 255u], 1u);
    }
    __syncthreads();

    // Inclusive scan over 256 node counts (all threads hit barriers)
    if (t < 256) incl[t] = hist[t];
    __syncthreads();
    for (int o = 1; o < 256; o <<= 1) {
        unsigned v = 0;
        if (t < 256 && t >= o) v = incl[t - o];
        __syncthreads();
        if (t < 256 && t >= o) incl[t] += v;
        __syncthreads();
    }
    if (t < 256) {
        exS[t] = incl[t] - hist[t];
        const int g = (int)(b << 8) + t;
        if (g < N) {
            float d  = (float)hist[t] + 1.0f;   // A + I
            float di = rsqrtf(d);
            deg[g]  = d;
            dinv[g] = di;
            y[g]    = x[g] * di;
            off[g]  = lo + exS[t];
        }
    }
    __syncthreads();

    // Phase B: re-read, rank, scatter (4B writes into this bucket's 68KB
    // range -> L2 accumulates full lines; R8 measured no write amplification)
    {
        unsigned i = t;
        for (; i + 3072 < cnt; i += 4096) {
            unsigned p0 = binned[lo + i];
            unsigned p1 = binned[lo + i + 1024];
            unsigned p2 = binned[lo + i + 2048];
            unsigned p3 = binned[lo + i + 3072];
            unsigned l0 = p0 & 255u, l1 = p1 & 255u;
            unsigned l2 = p2 & 255u, l3 = p3 & 255u;
            sorted[lo + exS[l0] + atomicAdd(&rk[l0], 1u)] = p0 >> 8;
            sorted[lo + exS[l1] + atomicAdd(&rk[l1], 1u)] = p1 >> 8;
            sorted[lo + exS[l2] + atomicAdd(&rk[l2], 1u)] = p2 >> 8;
            sorted[lo + exS[l3] + atomicAdd(&rk[l3], 1u)] = p3 >> 8;
        }
        for (; i < cnt; i += 1024) {
            unsigned p = binned[lo + i];
            unsigned l = p & 255u;
            sorted[lo + exS[l] + atomicAdd(&rk[l], 1u)] = p >> 8;
        }
    }
}

// 8 threads/node: atomic-free segmented sum of y[src]; fused layer-2 MLP.
__global__ __launch_bounds__(256) void k_agg1(const unsigned* __restrict__ sorted,
                                              const unsigned* __restrict__ off,
                                              const float* __restrict__ deg,
                                              const float* __restrict__ dinv,
                                              const float* __restrict__ x,
                                              const float* __restrict__ y,
                                              const float* __restrict__ W1,
                                              const float* __restrict__ b1,
                                              const float* __restrict__ W2, int N,
                                              float* __restrict__ z,
                                              float* __restrict__ zs) {
    const int tid = blockIdx.x * 256 + threadIdx.x;
    const int g   = tid >> 3;
    const int h   = tid & 7;
    if (g >= N) return;
    const float d   = deg[g];
    const int   n   = (int)d - 1;          // edge count of this node
    const unsigned lo = off[g];
    float acc = 0.0f;
    int i = h;
    for (; i + 8 < n; i += 16) {           // 2 independent gather chains
        unsigned s0 = sorted[lo + i];
        unsigned s1 = sorted[lo + i + 8];
        acc += y[s0];
        acc += y[s1];
    }
    for (; i < n; i += 8) acc += y[sorted[lo + i]];
    acc += __shfl_xor(acc, 1);
    acc += __shfl_xor(acc, 2);
    acc += __shfl_xor(acc, 4);
    // all 8 lanes hold the full sum; redundant compute, lane 0 stores
    float di  = dinv[g];
    float s1v = fmaf(di, acc, x[g] / d);
    float z0 = 0.0f, z1 = 0.0f;
#pragma unroll
    for (int f = 0; f < 16; ++f) {
        float hh = fmaxf(fmaf(s1v, W1[f], b1[f]), 0.0f);
        z0 = fmaf(hh, W2[2 * f + 0], z0);
        z1 = fmaf(hh, W2[2 * f + 1], z1);
    }
    if (h == 0) {
        ((float2*)z)[g]  = make_float2(z0, z1);
        ((float2*)zs)[g] = make_float2(z0 * di, z1 * di);
    }
}

// 8 threads/node: atomic-free segmented sum of zs[src]; fused log_softmax.
__global__ __launch_bounds__(256) void k_agg2(const unsigned* __restrict__ sorted,
                                              const unsigned* __restrict__ off,
                                              const float* __restrict__ deg,
                                              const float* __restrict__ dinv,
                                              const float* __restrict__ z,
                                              const float* __restrict__ zs,
                                              const float* __restrict__ b2, int N,
                                              float* __restrict__ out) {
    const int tid = blockIdx.x * 256 + threadIdx.x;
    const int g   = tid >> 3;
    const int h   = tid & 7;
    if (g >= N) return;
    const float d   = deg[g];
    const int   n   = (int)d - 1;
    const unsigned lo = off[g];
    const float2* zs2 = (const float2*)zs;
    float a0 = 0.0f, a1 = 0.0f;
    int i = h;
    for (; i + 8 < n; i += 16) {
        unsigned s0 = sorted[lo + i];
        unsigned s1 = sorted[lo + i + 8];
        float2 v0 = zs2[s0];
        float2 v1 = zs2[s1];
        a0 += v0.x + v1.x;
        a1 += v0.y + v1.y;
    }
    for (; i < n; i += 8) {
        float2 v = zs2[sorted[lo + i]];
        a0 += v.x;
        a1 += v.y;
    }
    a0 += __shfl_xor(a0, 1);
    a0 += __shfl_xor(a0, 2);
    a0 += __shfl_xor(a0, 4);
    a1 += __shfl_xor(a1, 1);
    a1 += __shfl_xor(a1, 2);
    a1 += __shfl_xor(a1, 4);
    if (h == 0) {
        float di   = dinv[g];
        float invd = 1.0f / d;
        float2 zz  = ((const float2*)z)[g];
        float o0 = fmaf(di, a0, zz.x * invd) + b2[0];
        float o1 = fmaf(di, a1, zz.y * invd) + b2[1];
        float m   = fmaxf(o0, o1);
        float lse = m + __logf(__expf(o0 - m) + __expf(o1 - m));
        ((float2*)out)[g] = make_float2(o0 - lse, o1 - lse);
    }
}

extern "C" void kernel_launch(void* const* d_in, const int* in_sizes, int n_in,
                              void* d_out, int out_size, void* d_ws, size_t ws_size,
                              hipStream_t stream) {
    const float* x  = (const float*)d_in[0];
    const int*   ei = (const int*)d_in[1];
    const float* W1 = (const float*)d_in[2];
    const float* b1 = (const float*)d_in[3];
    const float* W2 = (const float*)d_in[4];
    const float* b2 = (const float*)d_in[5];

    const int N = in_sizes[0];      // x is [N, 1]
    const int E = in_sizes[1] / 2;  // edge_index is [2, E]
    const int* src = ei;
    const int* dst = ei + E;

    const int NB = (N + 255) >> 8;  // 256-node buckets, NB <= 512

    // Workspace. z/zs alias the binned region (binned dead after k_sort).
    char* p = (char*)d_ws;
    unsigned* binned = (unsigned*)p;  p += ((size_t)NB * CAP + TILE) * 4;  // ~27.3 MB
    unsigned* sorted = (unsigned*)p;  p += (size_t)NB * CAP * 4;           // ~27.2 MB
    unsigned* off    = (unsigned*)p;  p += (size_t)N * 4;
    float* deg  = (float*)p;          p += (size_t)N * 4;
    float* dinv = (float*)p;          p += (size_t)N * 4;
    float* y    = (float*)p;          p += (size_t)N * 4;
    unsigned* cursor = (unsigned*)p;  p += (size_t)NB_MAX * 4;
    float* z  = (float*)binned;                    // [2N] written in k_agg1
    float* zs = ((float*)binned) + 2 * (size_t)N;  // [2N]

    const int nb_bin = (E + TILE - 1) / TILE;
    const int nb_agg = (8 * N + 255) / 256;

    k_init <<<1, 512, 0, stream>>>(NB, cursor);
    k_bin  <<<nb_bin, 256, 0, stream>>>(src, dst, E, NB, cursor, binned);
    k_sort <<<NB, 1024, 0, stream>>>(binned, cursor, x, N, sorted, off, deg, dinv, y);
    k_agg1 <<<nb_agg, 256, 0, stream>>>(sorted, off, deg, dinv, x, y, W1, b1, W2, N, z, zs);
    k_agg2 <<<nb_agg, 256, 0, stream>>>(sorted, off, deg, dinv, z, zs, b2, N, (float*)d_out);
}

// Round 10
// 228.565 us; speedup vs baseline: 1.3024x; 1.0458x over previous
//
#include <hip/hip_runtime.h>
#include <math.h>

// ---------------------------------------------------------------------------
// 2-layer GCN: counting-sort edges by dst + value-scatter, atomic-free sums.
//
// Evidence trail:
//  R2: global f32 atomicAdd = 32B HBM write each (~20G/s wall)  -> LDS agg.
//  R3: 4B scattered stores -> 32B sectors (5.7x write ampl)     -> LDS sort.
//  R7: LDS f32 atomic RMW throughput is the aggregation wall    -> sort +
//      atomic-free segmented sums.
//  R9: k_bin TILE 8192->4096 with halved atomics got SLOWER (49.7->55us):
//      per-tile scan/barrier overhead dominates, not atomic count. Scattered-
//      lane ops (~1cy/lane) are the currency: R9 spent 7/edge across 5 sweeps.
//  R10: TILE=8192 + 1-atomic k_bin; split sort into A(hist+node) and
//      B(rank + y-gather + uint2{src,y} value-scatter) so agg1 becomes a
//      fully COALESCED segmented sum (one sweep + 6.4M gathers eliminated).
//
// Pipeline:
//   k_init   cursor[b] = b*CAP
//   k_bin    8192-edge tiles, 512thr: reg-held rank multisplit -> binned[]
//   k_sortA  per bucket (1024thr): hist -> scan -> deg/dinv/y/off
//   k_sortB  per bucket (1024thr): rank + gather y[src] -> sorted2[pos] =
//            {src, y[src]}  (global barrier via kernel split makes y valid)
//   k_agg1   8 thr/node: COALESCED sum of sorted2[].y -> s1 -> MLP -> z, zs
//   k_agg2   8 thr/node: coalesced sorted2[].x + gather zs -> log_softmax
// Valid for N <= 131072 (NB <= 512), uniform-ish dst (CAP = mean+8sigma).
// ---------------------------------------------------------------------------

#define NB_MAX 512
#define CAP    17408u   // per-bucket capacity: E/NB=16368 avg, +8 sigma
#define TILE   8192
#define EPT    16       // edges per thread in k_bin (TILE/512)

__global__ __launch_bounds__(512) void k_init(int NB, unsigned* __restrict__ cursor) {
    int b = threadIdx.x;
    if (b < NB) cursor[b] = (unsigned)b * CAP;
}

// Multisplit by dst>>8. ONE LDS atomic per edge (rank at load, held in regs),
// scan -> LDS permute (plain writes) -> coalesced writeout. 512 threads.
__global__ __launch_bounds__(512) void k_bin(const int* __restrict__ src,
                                             const int* __restrict__ dst, int E, int NB,
                                             unsigned* __restrict__ cursor,
                                             unsigned* __restrict__ binned) {
    __shared__ unsigned cnt[NB_MAX];      // 2 KB
    __shared__ unsigned pfx[NB_MAX];      // 2 KB
    __shared__ unsigned lbase[NB_MAX];    // 2 KB
    __shared__ unsigned gbase[NB_MAX];    // 2 KB
    __shared__ unsigned svals[TILE];      // 32 KB
    __shared__ unsigned short sbkt[TILE]; // 16 KB  => 56 KB total, 2 blocks/CU

    const int lo = blockIdx.x * TILE;
    const int n  = min(E - lo, TILE);
    const int t  = threadIdx.x;
    const int nq    = n >> 2;             // int4 count
    const int ntail = n - (nq << 2);      // 0..3 leftover edges

    cnt[t] = 0;
    __syncthreads();

    const int4* d4 = (const int4*)(dst + lo);
    const int4* s4 = (const int4*)(src + lo);

    unsigned val[EPT];
    unsigned brk[EPT];                    // (bucket<<13) | rank ; 0xFFFFFFFF invalid

#pragma unroll
    for (int k = 0; k < 4; ++k) {
        const int j = t + (k << 9);       // + k*512
        if (j < nq) {
            int4 d = d4[j];
            int4 s = s4[j];
            {
                unsigned du = (unsigned)d.x, su = (unsigned)s.x;
                unsigned b = du >> 8;
                unsigned r = atomicAdd(&cnt[b], 1u);
                val[k * 4 + 0] = (su << 8) | (du & 255u);
                brk[k * 4 + 0] = (b << 13) | r;
            }
            {
                unsigned du = (unsigned)d.y, su = (unsigned)s.y;
                unsigned b = du >> 8;
                unsigned r = atomicAdd(&cnt[b], 1u);
                val[k * 4 + 1] = (su << 8) | (du & 255u);
                brk[k * 4 + 1] = (b << 13) | r;
            }
            {
                unsigned du = (unsigned)d.z, su = (unsigned)s.z;
                unsigned b = du >> 8;
                unsigned r = atomicAdd(&cnt[b], 1u);
                val[k * 4 + 2] = (su << 8) | (du & 255u);
                brk[k * 4 + 2] = (b << 13) | r;
            }
            {
                unsigned du = (unsigned)d.w, su = (unsigned)s.w;
                unsigned b = du >> 8;
                unsigned r = atomicAdd(&cnt[b], 1u);
                val[k * 4 + 3] = (su << 8) | (du & 255u);
                brk[k * 4 + 3] = (b << 13) | r;
            }
        } else {
            brk[k * 4 + 0] = 0xFFFFFFFFu; brk[k * 4 + 1] = 0xFFFFFFFFu;
            brk[k * 4 + 2] = 0xFFFFFFFFu; brk[k * 4 + 3] = 0xFFFFFFFFu;
            val[k * 4 + 0] = 0; val[k * 4 + 1] = 0;
            val[k * 4 + 2] = 0; val[k * 4 + 3] = 0;
        }
    }
    // tail edges (n % 4), one per thread t < ntail
    unsigned tval = 0, tbrk = 0xFFFFFFFFu;
    if (t < ntail) {
        unsigned du = (unsigned)dst[lo + (nq << 2) + t];
        unsigned su = (unsigned)src[lo + (nq << 2) + t];
        unsigned b = du >> 8;
        unsigned r = atomicAdd(&cnt[b], 1u);
        tval = (su << 8) | (du & 255u);
        tbrk = (b << 13) | r;
    }
    __syncthreads();

    // Inclusive scan over 512 bucket counts, 1 slot/thread
    pfx[t] = cnt[t];
    __syncthreads();
    for (int o = 1; o < NB_MAX; o <<= 1) {
        unsigned v = (t >= o) ? pfx[t - o] : 0u;
        __syncthreads();
        if (t >= o) pfx[t] += v;
        __syncthreads();
    }
    {
        unsigned c = cnt[t];
        lbase[t] = pfx[t] - c;
        gbase[t] = (t < NB && c) ? atomicAdd(&cursor[t], c) : 0u;
    }
    __syncthreads();

    // LDS permute: place each held edge at its in-tile sorted position
#pragma unroll
    for (int k = 0; k < EPT; ++k) {
        if (brk[k] != 0xFFFFFFFFu) {
            unsigned b = brk[k] >> 13, r = brk[k] & 8191u;
            unsigned pos = lbase[b] + r;
            svals[pos] = val[k];
            sbkt[pos]  = (unsigned short)b;
        }
    }
    if (tbrk != 0xFFFFFFFFu) {
        unsigned b = tbrk >> 13, r = tbrk & 8191u;
        unsigned pos = lbase[b] + r;
        svals[pos] = tval;
        sbkt[pos]  = (unsigned short)b;
    }
    __syncthreads();

    // Coalesced writeout: consecutive j share buckets => contiguous runs
    for (int j = t; j < n; j += 512) {
        unsigned b = sbkt[j];
        binned[gbase[b] + ((unsigned)j - lbase[b])] = svals[j];
    }
}

// Per bucket, 1024 threads: per-node histogram + scan + fused node pass.
__global__ __launch_bounds__(1024) void k_sortA(const unsigned* __restrict__ binned,
                                                const unsigned* __restrict__ cursor,
                                                const float* __restrict__ x, int N,
                                                unsigned* __restrict__ off,
                                                float* __restrict__ deg,
                                                float* __restrict__ dinv,
                                                float* __restrict__ y) {
    __shared__ unsigned hist[256];
    __shared__ unsigned incl[256];
    const int t = threadIdx.x;
    const unsigned b   = blockIdx.x;
    const unsigned lo  = b * CAP;
    const unsigned cnt = cursor[b] - lo;
    if (t < 256) hist[t] = 0;
    __syncthreads();

    // Histogram (4-way ILP, stride 1024)
    {
        unsigned i = t;
        for (; i + 3072 < cnt; i += 4096) {
            unsigned p0 = binned[lo + i];
            unsigned p1 = binned[lo + i + 1024];
            unsigned p2 = binned[lo + i + 2048];
            unsigned p3 = binned[lo + i + 3072];
            atomicAdd(&hist[p0 & 255u], 1u);
            atomicAdd(&hist[p1 & 255u], 1u);
            atomicAdd(&hist[p2 & 255u], 1u);
            atomicAdd(&hist[p3 & 255u], 1u);
        }
        for (; i < cnt; i += 1024) atomicAdd(&hist[binned[lo + i] & 255u], 1u);
    }
    __syncthreads();

    // Inclusive scan over 256 node counts (all threads hit barriers)
    if (t < 256) incl[t] = hist[t];
    __syncthreads();
    for (int o = 1; o < 256; o <<= 1) {
        unsigned v = 0;
        if (t < 256 && t >= o) v = incl[t - o];
        __syncthreads();
        if (t < 256 && t >= o) incl[t] += v;
        __syncthreads();
    }
    if (t < 256) {
        const int g = (int)(b << 8) + t;
        if (g < N) {
            float d  = (float)hist[t] + 1.0f;   // A + I
            float di = rsqrtf(d);
            deg[g]  = d;
            dinv[g] = di;
            y[g]    = x[g] * di;
            off[g]  = lo + (incl[t] - hist[t]);
        }
    }
}

// Per bucket, 1024 threads: rank + y-gather + value scatter.
// WITH_Y: sorted2[pos] = {src, y[src]} (8B). Else: sortedU[pos] = src (4B).
template <bool WITH_Y>
__global__ __launch_bounds__(1024) void k_sortB(const unsigned* __restrict__ binned,
                                                const unsigned* __restrict__ cursor,
                                                const unsigned* __restrict__ off,
                                                const float* __restrict__ y, int N,
                                                uint2* __restrict__ sorted2,
                                                unsigned* __restrict__ sortedU) {
    __shared__ unsigned rk[256];
    __shared__ unsigned offl[256];
    const int t = threadIdx.x;
    const unsigned b   = blockIdx.x;
    const unsigned lo  = b * CAP;
    const unsigned cnt = cursor[b] - lo;
    if (t < 256) {
        rk[t] = 0;
        const int g = (int)(b << 8) + t;
        offl[t] = (g < N) ? off[g] : 0u;
    }
    __syncthreads();

    unsigned i = t;
    for (; i + 3072 < cnt; i += 4096) {
        unsigned p0 = binned[lo + i];
        unsigned p1 = binned[lo + i + 1024];
        unsigned p2 = binned[lo + i + 2048];
        unsigned p3 = binned[lo + i + 3072];
        unsigned l0 = p0 & 255u, l1 = p1 & 255u, l2 = p2 & 255u, l3 = p3 & 255u;
        unsigned s0 = p0 >> 8,   s1 = p1 >> 8,   s2 = p2 >> 8,   s3 = p3 >> 8;
        unsigned q0 = offl[l0] + atomicAdd(&rk[l0], 1u);
        unsigned q1 = offl[l1] + atomicAdd(&rk[l1], 1u);
        unsigned q2 = offl[l2] + atomicAdd(&rk[l2], 1u);
        unsigned q3 = offl[l3] + atomicAdd(&rk[l3], 1u);
        if (WITH_Y) {
            sorted2[q0] = make_uint2(s0, __float_as_uint(y[s0]));
            sorted2[q1] = make_uint2(s1, __float_as_uint(y[s1]));
            sorted2[q2] = make_uint2(s2, __float_as_uint(y[s2]));
            sorted2[q3] = make_uint2(s3, __float_as_uint(y[s3]));
        } else {
            sortedU[q0] = s0;
            sortedU[q1] = s1;
            sortedU[q2] = s2;
            sortedU[q3] = s3;
        }
    }
    for (; i < cnt; i += 1024) {
        unsigned p = binned[lo + i];
        unsigned l = p & 255u, s = p >> 8;
        unsigned q = offl[l] + atomicAdd(&rk[l], 1u);
        if (WITH_Y) sorted2[q] = make_uint2(s, __float_as_uint(y[s]));
        else        sortedU[q] = s;
    }
}

// 8 thr/node: segmented sum of y (coalesced if WITH_Y) + fused layer-2 MLP.
template <bool WITH_Y>
__global__ __launch_bounds__(256) void k_agg1(const uint2* __restrict__ sorted2,
                                              const unsigned* __restrict__ sortedU,
                                              const unsigned* __restrict__ off,
                                              const float* __restrict__ deg,
                                              const float* __restrict__ dinv,
                                              const float* __restrict__ x,
                                              const float* __restrict__ y,
                                              const float* __restrict__ W1,
                                              const float* __restrict__ b1,
                                              const float* __restrict__ W2, int N,
                                              float* __restrict__ z,
                                              float* __restrict__ zs) {
    const int tid = blockIdx.x * 256 + threadIdx.x;
    const int g   = tid >> 3;
    const int h   = tid & 7;
    if (g >= N) return;
    const float d   = deg[g];
    const int   n   = (int)d - 1;
    const unsigned lo = off[g];
    float acc = 0.0f;
    int i = h;
    for (; i + 8 < n; i += 16) {
        if (WITH_Y) {
            acc += __uint_as_float(sorted2[lo + i].y);
            acc += __uint_as_float(sorted2[lo + i + 8].y);
        } else {
            unsigned s0 = sortedU[lo + i];
            unsigned s1 = sortedU[lo + i + 8];
            acc += y[s0];
            acc += y[s1];
        }
    }
    for (; i < n; i += 8)
        acc += WITH_Y ? __uint_as_float(sorted2[lo + i].y) : y[sortedU[lo + i]];
    acc += __shfl_xor(acc, 1);
    acc += __shfl_xor(acc, 2);
    acc += __shfl_xor(acc, 4);
    float di  = dinv[g];
    float s1v = fmaf(di, acc, x[g] / d);
    float z0 = 0.0f, z1 = 0.0f;
#pragma unroll
    for (int f = 0; f < 16; ++f) {
        float hh = fmaxf(fmaf(s1v, W1[f], b1[f]), 0.0f);
        z0 = fmaf(hh, W2[2 * f + 0], z0);
        z1 = fmaf(hh, W2[2 * f + 1], z1);
    }
    if (h == 0) {
        ((float2*)z)[g]  = make_float2(z0, z1);
        ((float2*)zs)[g] = make_float2(z0 * di, z1 * di);
    }
}

// 8 thr/node: segmented sum of zs[src] (src from sorted2.x) + log_softmax.
template <bool WITH_Y>
__global__ __launch_bounds__(256) void k_agg2(const uint2* __restrict__ sorted2,
                                              const unsigned* __restrict__ sortedU,
                                              const unsigned* __restrict__ off,
                                              const float* __restrict__ deg,
                                              const float* __restrict__ dinv,
                                              const float* __restrict__ z,
                                              const float* __restrict__ zs,
                                              const float* __restrict__ b2, int N,
                                              float* __restrict__ out) {
    const int tid = blockIdx.x * 256 + threadIdx.x;
    const int g   = tid >> 3;
    const int h   = tid & 7;
    if (g >= N) return;
    const float d   = deg[g];
    const int   n   = (int)d - 1;
    const unsigned lo = off[g];
    const float2* zs2 = (const float2*)zs;
    float a0 = 0.0f, a1 = 0.0f;
    int i = h;
    for (; i + 8 < n; i += 16) {
        unsigned s0 = WITH_Y ? sorted2[lo + i].x     : sortedU[lo + i];
        unsigned s1 = WITH_Y ? sorted2[lo + i + 8].x : sortedU[lo + i + 8];
        float2 v0 = zs2[s0];
        float2 v1 = zs2[s1];
        a0 += v0.x + v1.x;
        a1 += v0.y + v1.y;
    }
    for (; i < n; i += 8) {
        unsigned s = WITH_Y ? sorted2[lo + i].x : sortedU[lo + i];
        float2 v = zs2[s];
        a0 += v.x;
        a1 += v.y;
    }
    a0 += __shfl_xor(a0, 1);
    a0 += __shfl_xor(a0, 2);
    a0 += __shfl_xor(a0, 4);
    a1 += __shfl_xor(a1, 1);
    a1 += __shfl_xor(a1, 2);
    a1 += __shfl_xor(a1, 4);
    if (h == 0) {
        float di   = dinv[g];
        float invd = 1.0f / d;
        float2 zz  = ((const float2*)z)[g];
        float o0 = fmaf(di, a0, zz.x * invd) + b2[0];
        float o1 = fmaf(di, a1, zz.y * invd) + b2[1];
        float m   = fmaxf(o0, o1);
        float lse = m + __logf(__expf(o0 - m) + __expf(o1 - m));
        ((float2*)out)[g] = make_float2(o0 - lse, o1 - lse);
    }
}

extern "C" void kernel_launch(void* const* d_in, const int* in_sizes, int n_in,
                              void* d_out, int out_size, void* d_ws, size_t ws_size,
                              hipStream_t stream) {
    const float* x  = (const float*)d_in[0];
    const int*   ei = (const int*)d_in[1];
    const float* W1 = (const float*)d_in[2];
    const float* b1 = (const float*)d_in[3];
    const float* W2 = (const float*)d_in[4];
    const float* b2 = (const float*)d_in[5];

    const int N = in_sizes[0];      // x is [N, 1]
    const int E = in_sizes[1] / 2;  // edge_index is [2, E]
    const int* src = ei;
    const int* dst = ei + E;

    const int NB = (N + 255) >> 8;  // 256-node buckets, NB <= 512

    const size_t binned_b = ((size_t)NB * CAP + TILE) * 4;   // ~27.3 MB
    const size_t node_b   = (size_t)N * 4;
    const size_t s2_b     = (size_t)NB * CAP * 8;            // ~54.5 MB
    const size_t sU_b     = (size_t)NB * CAP * 4;            // ~27.2 MB
    const size_t fixed_b  = binned_b + 4 * node_b + (size_t)NB_MAX * 4 + 256;
    const bool with_y = (fixed_b + s2_b) <= ws_size;

    char* p = (char*)d_ws;
    unsigned* binned = (unsigned*)p;  p += binned_b;
    uint2*    sorted2 = (uint2*)p;
    unsigned* sortedU = (unsigned*)p; p += (with_y ? s2_b : sU_b);
    unsigned* off    = (unsigned*)p;  p += node_b;
    float* deg  = (float*)p;          p += node_b;
    float* dinv = (float*)p;          p += node_b;
    float* y    = (float*)p;          p += node_b;
    unsigned* cursor = (unsigned*)p;  p += (size_t)NB_MAX * 4;
    float* z  = (float*)binned;                    // alias: binned dead after sortB
    float* zs = ((float*)binned) + 2 * (size_t)N;

    const int nb_bin = (E + TILE - 1) / TILE;
    const int nb_agg = (8 * N + 255) / 256;

    k_init  <<<1, 512, 0, stream>>>(NB, cursor);
    k_bin   <<<nb_bin, 512, 0, stream>>>(src, dst, E, NB, cursor, binned);
    k_sortA <<<NB, 1024, 0, stream>>>(binned, cursor, x, N, off, deg, dinv, y);
    if (with_y) {
        k_sortB<true><<<NB, 1024, 0, stream>>>(binned, cursor, off, y, N, sorted2, sortedU);
        k_agg1<true><<<nb_agg, 256, 0, stream>>>(sorted2, sortedU, off, deg, dinv, x, y,
                                                 W1, b1, W2, N, z, zs);
        k_agg2<true><<<nb_agg, 256, 0, stream>>>(sorted2, sortedU, off, deg, dinv, z, zs,
                                                 b2, N, (float*)d_out);
    } else {
        k_sortB<false><<<NB, 1024, 0, stream>>>(binned, cursor, off, y, N, sorted2, sortedU);
        k_agg1<false><<<nb_agg, 256, 0, stream>>>(sorted2, sortedU, off, deg, dinv, x, y,
                                                  W1, b1, W2, N, z, zs);
        k_agg2<false><<<nb_agg, 256, 0, stream>>>(sorted2, sortedU, off, deg, dinv, z, zs,
                                                  b2, N, (float*)d_out);
    }
}

// Round 11
// 193.164 us; speedup vs baseline: 1.5410x; 1.1833x over previous
//
#include <hip/hip_runtime.h>
#include <math.h>

// ---------------------------------------------------------------------------
// 2-layer GCN: counting-sort edges by dst; full-bucket LDS value staging.
//
// Evidence trail:
//  R2:  global f32 atomicAdd = 32B HBM write each -> LDS aggregation.
//  R3:  scattered 4B stores -> 32B sectors (5.7x ampl) -> LDS-stage + coalesce.
//  R7:  LDS f32 atomic RMW is the aggregation wall -> sort + atomic-free sums.
//  R9:  per-tile scan/barrier overhead dominates k_bin, not atomic count.
//  R10: sortB's scattered 8B value-writes = 107MB HBM write (2.1x ampl) and
//       agg1 re-reads 51MB. -> stage WHOLE bucket (srt+y = 136KB) in LDS:
//       coalesced 4B writeout + in-LDS segmented sums (agg1 fused, deleted).
//
// Pipeline:
//   k_init   cursor[b] = b*CAP
//   k_bin    16384-edge tiles, 1024thr: 1-atomic reg-rank multisplit -> binned
//   k_sortA  per bucket (1024thr): hist -> scan -> deg/dinv/y/off
//   k_sortB  per bucket (1024thr, 138KB LDS): rank + y-gather into LDS at
//            sorted pos -> coalesced src writeout -> in-LDS 4thr/node seg-sum
//            -> s1 -> 16x relu-FMA -> z, zs   (fuses old agg1)
//   k_agg2   8 thr/node: coalesced src + zs gather -> o -> log_softmax
// Valid for N <= 131072 (NB <= 512), uniform-ish dst (CAP = mean+8sigma).
// ---------------------------------------------------------------------------

#define NB_MAX 512
#define CAP    17408u   // per-bucket capacity: E/NB=16368 avg, +8 sigma
#define TILE   16384
#define EPT    16       // edges per thread in k_bin (TILE/1024)

__global__ __launch_bounds__(512) void k_init(int NB, unsigned* __restrict__ cursor) {
    int b = threadIdx.x;
    if (b < NB) cursor[b] = (unsigned)b * CAP;
}

// Multisplit by dst>>8. ONE LDS atomic per edge (rank at load, held in regs),
// scan -> LDS permute (plain writes) -> coalesced writeout. 1024 threads.
__global__ __launch_bounds__(1024) void k_bin(const int* __restrict__ src,
                                              const int* __restrict__ dst, int E, int NB,
                                              unsigned* __restrict__ cursor,
                                              unsigned* __restrict__ binned) {
    __shared__ unsigned cnt[NB_MAX];      // 2 KB
    __shared__ unsigned pfx[NB_MAX];      // 2 KB
    __shared__ unsigned lbase[NB_MAX];    // 2 KB
    __shared__ unsigned gbase[NB_MAX];    // 2 KB
    __shared__ unsigned svals[TILE];      // 64 KB
    __shared__ unsigned short sbkt[TILE]; // 32 KB  => ~104 KB, 1 block/CU

    const int lo = blockIdx.x * TILE;
    const int n  = min(E - lo, TILE);
    const int t  = threadIdx.x;
    const int nq    = n >> 2;             // int4 count
    const int ntail = n - (nq << 2);      // 0..3 leftover edges

    if (t < NB_MAX) cnt[t] = 0;
    __syncthreads();

    const int4* d4 = (const int4*)(dst + lo);
    const int4* s4 = (const int4*)(src + lo);

    unsigned val[EPT];
    unsigned brk[EPT];                    // (bucket<<14) | rank ; 0xFFFFFFFF invalid

#pragma unroll
    for (int k = 0; k < 4; ++k) {
        const int j = t + (k << 10);      // + k*1024
        if (j < nq) {
            int4 d = d4[j];
            int4 s = s4[j];
            {
                unsigned du = (unsigned)d.x, su = (unsigned)s.x;
                unsigned b = du >> 8;
                unsigned r = atomicAdd(&cnt[b], 1u);
                val[k * 4 + 0] = (su << 8) | (du & 255u);
                brk[k * 4 + 0] = (b << 14) | r;
            }
            {
                unsigned du = (unsigned)d.y, su = (unsigned)s.y;
                unsigned b = du >> 8;
                unsigned r = atomicAdd(&cnt[b], 1u);
                val[k * 4 + 1] = (su << 8) | (du & 255u);
                brk[k * 4 + 1] = (b << 14) | r;
            }
            {
                unsigned du = (unsigned)d.z, su = (unsigned)s.z;
                unsigned b = du >> 8;
                unsigned r = atomicAdd(&cnt[b], 1u);
                val[k * 4 + 2] = (su << 8) | (du & 255u);
                brk[k * 4 + 2] = (b << 14) | r;
            }
            {
                unsigned du = (unsigned)d.w, su = (unsigned)s.w;
                unsigned b = du >> 8;
                unsigned r = atomicAdd(&cnt[b], 1u);
                val[k * 4 + 3] = (su << 8) | (du & 255u);
                brk[k * 4 + 3] = (b << 14) | r;
            }
        } else {
            brk[k * 4 + 0] = 0xFFFFFFFFu; brk[k * 4 + 1] = 0xFFFFFFFFu;
            brk[k * 4 + 2] = 0xFFFFFFFFu; brk[k * 4 + 3] = 0xFFFFFFFFu;
            val[k * 4 + 0] = 0; val[k * 4 + 1] = 0;
            val[k * 4 + 2] = 0; val[k * 4 + 3] = 0;
        }
    }
    // tail edges (n % 4), one per thread t < ntail
    unsigned tval = 0, tbrk = 0xFFFFFFFFu;
    if (t < ntail) {
        unsigned du = (unsigned)dst[lo + (nq << 2) + t];
        unsigned su = (unsigned)src[lo + (nq << 2) + t];
        unsigned b = du >> 8;
        unsigned r = atomicAdd(&cnt[b], 1u);
        tval = (su << 8) | (du & 255u);
        tbrk = (b << 14) | r;
    }
    __syncthreads();

    // Inclusive scan over 512 bucket counts (threads 0..511)
    if (t < NB_MAX) pfx[t] = cnt[t];
    __syncthreads();
    for (int o = 1; o < NB_MAX; o <<= 1) {
        unsigned v = 0;
        if (t < NB_MAX && t >= o) v = pfx[t - o];
        __syncthreads();
        if (t < NB_MAX && t >= o) pfx[t] += v;
        __syncthreads();
    }
    if (t < NB_MAX) {
        unsigned c = cnt[t];
        lbase[t] = pfx[t] - c;
        gbase[t] = (t < NB && c) ? atomicAdd(&cursor[t], c) : 0u;
    }
    __syncthreads();

    // LDS permute: place each held edge at its in-tile sorted position
#pragma unroll
    for (int k = 0; k < EPT; ++k) {
        if (brk[k] != 0xFFFFFFFFu) {
            unsigned b = brk[k] >> 14, r = brk[k] & 16383u;
            unsigned pos = lbase[b] + r;
            svals[pos] = val[k];
            sbkt[pos]  = (unsigned short)b;
        }
    }
    if (tbrk != 0xFFFFFFFFu) {
        unsigned b = tbrk >> 14, r = tbrk & 16383u;
        unsigned pos = lbase[b] + r;
        svals[pos] = tval;
        sbkt[pos]  = (unsigned short)b;
    }
    __syncthreads();

    // Coalesced writeout: consecutive j share buckets => contiguous runs
    for (int j = t; j < n; j += 1024) {
        unsigned b = sbkt[j];
        binned[gbase[b] + ((unsigned)j - lbase[b])] = svals[j];
    }
}

// Per bucket, 1024 threads: per-node histogram + scan + fused node pass.
__global__ __launch_bounds__(1024) void k_sortA(const unsigned* __restrict__ binned,
                                                const unsigned* __restrict__ cursor,
                                                const float* __restrict__ x, int N,
                                                unsigned* __restrict__ off,
                                                float* __restrict__ deg,
                                                float* __restrict__ dinv,
                                                float* __restrict__ y) {
    __shared__ unsigned hist[256];
    __shared__ unsigned incl[256];
    const int t = threadIdx.x;
    const unsigned b   = blockIdx.x;
    const unsigned lo  = b * CAP;
    const unsigned cnt = cursor[b] - lo;
    if (t < 256) hist[t] = 0;
    __syncthreads();

    // Histogram (4-way ILP, stride 1024)
    {
        unsigned i = t;
        for (; i + 3072 < cnt; i += 4096) {
            unsigned p0 = binned[lo + i];
            unsigned p1 = binned[lo + i + 1024];
            unsigned p2 = binned[lo + i + 2048];
            unsigned p3 = binned[lo + i + 3072];
            atomicAdd(&hist[p0 & 255u], 1u);
            atomicAdd(&hist[p1 & 255u], 1u);
            atomicAdd(&hist[p2 & 255u], 1u);
            atomicAdd(&hist[p3 & 255u], 1u);
        }
        for (; i < cnt; i += 1024) atomicAdd(&hist[binned[lo + i] & 255u], 1u);
    }
    __syncthreads();

    // Inclusive scan over 256 node counts (all threads hit barriers)
    if (t < 256) incl[t] = hist[t];
    __syncthreads();
    for (int o = 1; o < 256; o <<= 1) {
        unsigned v = 0;
        if (t < 256 && t >= o) v = incl[t - o];
        __syncthreads();
        if (t < 256 && t >= o) incl[t] += v;
        __syncthreads();
    }
    if (t < 256) {
        const int g = (int)(b << 8) + t;
        if (g < N) {
            float d  = (float)hist[t] + 1.0f;   // A + I
            float di = rsqrtf(d);
            deg[g]  = d;
            dinv[g] = di;
            y[g]    = x[g] * di;
            off[g]  = lo + (incl[t] - hist[t]);
        }
    }
}

// Per bucket, 1024 thr, ~138KB LDS: rank + y-gather into LDS at sorted pos,
// coalesced src writeout, in-LDS segmented sums + layer-2 MLP (fused agg1).
__global__ __launch_bounds__(1024) void k_sortB(const unsigned* __restrict__ binned,
                                                const unsigned* __restrict__ cursor,
                                                const unsigned* __restrict__ off,
                                                const float* __restrict__ deg,
                                                const float* __restrict__ dinv,
                                                const float* __restrict__ x,
                                                const float* __restrict__ y,
                                                const float* __restrict__ W1,
                                                const float* __restrict__ b1,
                                                const float* __restrict__ W2, int N,
                                                unsigned* __restrict__ sorted,
                                                float* __restrict__ z,
                                                float* __restrict__ zs) {
    __shared__ unsigned srt[CAP];   // 69632 B
    __shared__ float    yv[CAP];    // 69632 B
    __shared__ unsigned rk[256];    // 1 KB
    __shared__ unsigned offl[256];  // 1 KB   => ~138 KB total
    const int t = threadIdx.x;
    const unsigned b   = blockIdx.x;
    const unsigned lo  = b * CAP;
    const unsigned cnt = cursor[b] - lo;
    if (t < 256) {
        rk[t] = 0;
        const int g = (int)(b << 8) + t;
        offl[t] = (g < N) ? (off[g] - lo) : 0u;
    }
    __syncthreads();

    // Stage: rank, gather y[src], place {src,y} at final sorted LDS position
    {
        unsigned i = t;
        for (; i + 3072 < cnt; i += 4096) {
            unsigned p0 = binned[lo + i];
            unsigned p1 = binned[lo + i + 1024];
            unsigned p2 = binned[lo + i + 2048];
            unsigned p3 = binned[lo + i + 3072];
            unsigned l0 = p0 & 255u, l1 = p1 & 255u, l2 = p2 & 255u, l3 = p3 & 255u;
            unsigned s0 = p0 >> 8,   s1 = p1 >> 8,   s2 = p2 >> 8,   s3 = p3 >> 8;
            float y0 = y[s0], y1 = y[s1], y2 = y[s2], y3 = y[s3];
            unsigned q0 = offl[l0] + atomicAdd(&rk[l0], 1u);
            unsigned q1 = offl[l1] + atomicAdd(&rk[l1], 1u);
            unsigned q2 = offl[l2] + atomicAdd(&rk[l2], 1u);
            unsigned q3 = offl[l3] + atomicAdd(&rk[l3], 1u);
            srt[q0] = s0; yv[q0] = y0;
            srt[q1] = s1; yv[q1] = y1;
            srt[q2] = s2; yv[q2] = y2;
            srt[q3] = s3; yv[q3] = y3;
        }
        for (; i < cnt; i += 1024) {
            unsigned p = binned[lo + i];
            unsigned l = p & 255u, s = p >> 8;
            unsigned q = offl[l] + atomicAdd(&rk[l], 1u);
            srt[q] = s;
            yv[q]  = y[s];
        }
    }
    __syncthreads();

    // Coalesced writeout of sorted src indices (for k_agg2)
    for (unsigned j = t; j < cnt; j += 1024) sorted[lo + j] = srt[j];

    // In-LDS segmented sum, 4 threads per node; fused layer-2 MLP
    {
        const int ln = t >> 2;          // local node 0..255
        const int h  = t & 3;
        const int g  = (int)(b << 8) + ln;
        if (g < N) {
            const float d  = deg[g];
            const int   n  = (int)d - 1;
            const unsigned base = offl[ln];
            float acc = 0.0f;
            for (int i = h; i < n; i += 4) acc += yv[base + i];
            acc += __shfl_xor(acc, 1);
            acc += __shfl_xor(acc, 2);
            float di  = dinv[g];
            float s1v = fmaf(di, acc, x[g] / d);
            float z0 = 0.0f, z1 = 0.0f;
#pragma unroll
            for (int f = 0; f < 16; ++f) {
                float hh = fmaxf(fmaf(s1v, W1[f], b1[f]), 0.0f);
                z0 = fmaf(hh, W2[2 * f + 0], z0);
                z1 = fmaf(hh, W2[2 * f + 1], z1);
            }
            if (h == 0) {
                ((float2*)z)[g]  = make_float2(z0, z1);
                ((float2*)zs)[g] = make_float2(z0 * di, z1 * di);
            }
        }
    }
}

// 8 thr/node: coalesced src read + zs gather; fused log_softmax.
__global__ __launch_bounds__(256) void k_agg2(const unsigned* __restrict__ sorted,
                                              const unsigned* __restrict__ off,
                                              const float* __restrict__ deg,
                                              const float* __restrict__ dinv,
                                              const float* __restrict__ z,
                                              const float* __restrict__ zs,
                                              const float* __restrict__ b2, int N,
                                              float* __restrict__ out) {
    const int tid = blockIdx.x * 256 + threadIdx.x;
    const int g   = tid >> 3;
    const int h   = tid & 7;
    if (g >= N) return;
    const float d   = deg[g];
    const int   n   = (int)d - 1;
    const unsigned lo = off[g];
    const float2* zs2 = (const float2*)zs;
    float a0 = 0.0f, a1 = 0.0f;
    int i = h;
    for (; i + 8 < n; i += 16) {
        unsigned s0 = sorted[lo + i];
        unsigned s1 = sorted[lo + i + 8];
        float2 v0 = zs2[s0];
        float2 v1 = zs2[s1];
        a0 += v0.x + v1.x;
        a1 += v0.y + v1.y;
    }
    for (; i < n; i += 8) {
        float2 v = zs2[sorted[lo + i]];
        a0 += v.x;
        a1 += v.y;
    }
    a0 += __shfl_xor(a0, 1);
    a0 += __shfl_xor(a0, 2);
    a0 += __shfl_xor(a0, 4);
    a1 += __shfl_xor(a1, 1);
    a1 += __shfl_xor(a1, 2);
    a1 += __shfl_xor(a1, 4);
    if (h == 0) {
        float di   = dinv[g];
        float invd = 1.0f / d;
        float2 zz  = ((const float2*)z)[g];
        float o0 = fmaf(di, a0, zz.x * invd) + b2[0];
        float o1 = fmaf(di, a1, zz.y * invd) + b2[1];
        float m   = fmaxf(o0, o1);
        float lse = m + __logf(__expf(o0 - m) + __expf(o1 - m));
        ((float2*)out)[g] = make_float2(o0 - lse, o1 - lse);
    }
}

extern "C" void kernel_launch(void* const* d_in, const int* in_sizes, int n_in,
                              void* d_out, int out_size, void* d_ws, size_t ws_size,
                              hipStream_t stream) {
    const float* x  = (const float*)d_in[0];
    const int*   ei = (const int*)d_in[1];
    const float* W1 = (const float*)d_in[2];
    const float* b1 = (const float*)d_in[3];
    const float* W2 = (const float*)d_in[4];
    const float* b2 = (const float*)d_in[5];

    const int N = in_sizes[0];      // x is [N, 1]
    const int E = in_sizes[1] / 2;  // edge_index is [2, E]
    const int* src = ei;
    const int* dst = ei + E;

    const int NB = (N + 255) >> 8;  // 256-node buckets, NB <= 512

    // Workspace (~58 MB), NO aliasing (k_sortB writes z/zs while other
    // blocks still read binned).
    char* p = (char*)d_ws;
    unsigned* binned = (unsigned*)p;  p += ((size_t)NB * CAP + TILE) * 4;  // ~27.3 MB
    unsigned* sorted = (unsigned*)p;  p += (size_t)NB * CAP * 4;           // ~27.2 MB
    unsigned* off    = (unsigned*)p;  p += (size_t)N * 4;
    float* deg  = (float*)p;          p += (size_t)N * 4;
    float* dinv = (float*)p;          p += (size_t)N * 4;
    float* y    = (float*)p;          p += (size_t)N * 4;
    float* z    = (float*)p;          p += (size_t)2 * N * 4;
    float* zs   = (float*)p;          p += (size_t)2 * N * 4;
    unsigned* cursor = (unsigned*)p;  p += (size_t)NB_MAX * 4;

    const int nb_bin = (E + TILE - 1) / TILE;
    const int nb_agg = (8 * N + 255) / 256;

    k_init  <<<1, 512, 0, stream>>>(NB, cursor);
    k_bin   <<<nb_bin, 1024, 0, stream>>>(src, dst, E, NB, cursor, binned);
    k_sortA <<<NB, 1024, 0, stream>>>(binned, cursor, x, N, off, deg, dinv, y);
    k_sortB <<<NB, 1024, 0, stream>>>(binned, cursor, off, deg, dinv, x, y,
                                      W1, b1, W2, N, sorted, z, zs);
    k_agg2  <<<nb_agg, 256, 0, stream>>>(sorted, off, deg, dinv, z, zs, b2, N,
                                         (float*)d_out);
}